// Round 11
// baseline (4636.620 us; speedup 1.0000x reference)
//
#include <hip/hip_runtime.h>

#define B_    64
#define T_    1024
#define IN_   64
#define H_    512
#define OUT_  64
#define SLOTS 8
#define NWG   256
#define NROLE 130
#define NWORD 6144      // words per (bhalf, slot): 32 jt * 32 rows * 6 words
#define RSLOT (8*NWORD) // words per ring (8 slots)

typedef _Float16 f16;
typedef _Float16 half8 __attribute__((ext_vector_type(8)));
typedef float    floatx4 __attribute__((ext_vector_type(4)));
typedef unsigned int u32;
typedef unsigned short u16;
typedef unsigned long long u64;

#define MFMA16(a,b,c) __builtin_amdgcn_mfma_f32_16x16x32_f16((a),(b),(c),0,0,0)

// LDS layout (158720 B, 1 WG/CU)
#define XS_OFF   0        // 8KB: L1 x-stage (L2 reuses first 4B as esc flag)
#define HB_OFF   8192     // 1KB: pointwise h output (f16[512])
#define CC_OFF   9216     // 2KB: c-state
#define RED_OFF  11264    // 32KB: 4 kq-regions x 8KB partial-sum
#define H1W_OFF  44032    // 57344: packed h words (h1 for L1/L2; h2 for head)
#define H2W_OFF  101376   // 57344: packed h2 words (L2 pass B; L1 reuses first 4B as esc)

__device__ __forceinline__ float sigmoidf_(float x) {
    return 1.0f / (1.0f + __expf(-x));
}
__device__ __forceinline__ float tanhf_(float x) {
    float ax = fabsf(x);
    float e  = __expf(-2.0f * ax);
    float t  = (1.0f - e) / (1.0f + e);
    return x >= 0.0f ? t : -t;
}

// Flags: agent-scope RMW + agent-scope poll (proven R2/R5). Back-pressure edges only.
__device__ __forceinline__ u32 flag_peek(const u32* p) {
    return __hip_atomic_load(p, __ATOMIC_RELAXED, __HIP_MEMORY_SCOPE_AGENT);
}
__device__ __forceinline__ void wait_ge(u32* p, u32 v) {
    while (__hip_atomic_load(p, __ATOMIC_RELAXED, __HIP_MEMORY_SCOPE_AGENT) < v)
        __builtin_amdgcn_s_sleep(1);
}
__device__ __forceinline__ void flag_add(u32* p) {
    __hip_atomic_fetch_add(p, 1u, __ATOMIC_RELAXED, __HIP_MEMORY_SCOPE_AGENT);
}
// System-scope tagged-word ops (MALL coherence point) -- cross-XCD edges. Proven R9.
__device__ __forceinline__ void astore8w(u64* p, u64 v) {
    __hip_atomic_store(p, v, __ATOMIC_RELAXED, __HIP_MEMORY_SCOPE_SYSTEM);
}
__device__ __forceinline__ u64 aload8w(const u64* p) {
    return __hip_atomic_load(p, __ATOMIC_RELAXED, __HIP_MEMORY_SCOPE_SYSTEM);
}
// Agent-scope tagged-word ops -- intra-XCD ring edges (shared XCD L2 is the
// physical coherence point when all ring members sit on one XCD). Proven R14
// (FETCH_SIZE 866->215 MB).
__device__ __forceinline__ void astore8a(u64* p, u64 v) {
    __hip_atomic_store(p, v, __ATOMIC_RELAXED, __HIP_MEMORY_SCOPE_AGENT);
}
__device__ __forceinline__ u64 aload8a(const u64* p) {
    return __hip_atomic_load(p, __ATOMIC_RELAXED, __HIP_MEMORY_SCOPE_AGENT);
}

// Poll-stage ONE 49KB tagged buffer (6144 words) into LDS. 12-load rounds (R11
// lesson: never widen rounds).
__device__ __forceinline__ void stage_poll(char* smem, int ldsOff, const u64* g,
                                           u32 exp, int tid, const int* soff) {
    u32 pend = 0xFFFu;
    do {
        u64 vv[12];
        #pragma unroll
        for (int i = 0; i < 12; ++i)
            vv[i] = aload8w(g + i*512 + tid);
        #pragma unroll
        for (int i = 0; i < 12; ++i) {
            if ((pend & (1u << i)) && (u32)(vv[i] >> 48) == exp) {
                *(u64*)(smem + ldsOff + soff[i]) = vv[i];
                pend &= ~(1u << i);
            }
        }
        if (pend) __builtin_amdgcn_s_sleep(1);
    } while (pend);
}

// Ring poll: agent-scope loads from the ring copy (gr) when the ring is
// XCD-coherent; system loads from the always-published system copy (gs) when
// not, or after a sticky escape (safety: completes even if agent semantics
// differ from the hypothesis -- at R9 speed, never wrong, never hung).
__device__ __forceinline__ void stage_poll_r(char* smem, int ldsOff,
                                             const u64* gr, const u64* gs,
                                             u32 exp, int tid, const int* soff,
                                             int coh, int* esc) {
    u32 pend = 0xFFFu;
    int rounds = 0;
    bool useSys = (!coh) || (*esc != 0);
    do {
        u64 vv[12];
        if (!useSys) {
            #pragma unroll
            for (int i = 0; i < 12; ++i) vv[i] = aload8a(gr + i*512 + tid);
        } else {
            #pragma unroll
            for (int i = 0; i < 12; ++i) vv[i] = aload8w(gs + i*512 + tid);
        }
        #pragma unroll
        for (int i = 0; i < 12; ++i) {
            if ((pend & (1u << i)) && (u32)(vv[i] >> 48) == exp) {
                *(u64*)(smem + ldsOff + soff[i]) = vv[i];
                pend &= ~(1u << i);
            }
        }
        if (pend) {
            __builtin_amdgcn_s_sleep(1);
            if (!useSys && ++rounds >= 1024) { useSys = true; *esc = 1; }
        }
    } while (pend);
}

// Build a half8 fragment (8 consecutive k-values) from 3 packed LDS words.
__device__ __forceinline__ half8 frag_pk(const char* p) {
    const u64* q = (const u64*)p;
    u64 w0 = q[0], w1 = q[1], w2 = q[2];
    u32 b = (u32)(w0 >> 32), c = (u32)w1, d = (u32)(w1 >> 32);
    union { u32 u[4]; half8 h; } U;
    U.u[0] = (u32)w0;
    U.u[1] = (b & 0xffffu) | (c << 16);
    U.u[2] = (c >> 16) | (d << 16);
    U.u[3] = (u32)w2;
    return U.h;
}
// LDS byte offset of word (jt, row, wi): ((jt*32+row)*7 + wi)*8
#define WB(jt,row,wi) (((jt)*224 + (row)*7 + (wi)) * 8)

// ---------------- prep kernels (weights -> fp16 fragment-linear) ----------------
__global__ void pack_w1(const float* __restrict__ Wih, const float* __restrict__ Whh,
                        f16* __restrict__ Wp) {
    int idx = blockIdx.x * 256 + threadIdx.x;
    if (idx >= 4*32*18*512) return;
    int j    = idx & 7;
    int lane = (idx >> 3) & 63;
    int kt   = (idx >> 9) % 18;
    int r    = (idx >> 9) / 18;
    int jt   = r & 31;
    int g    = r >> 5;
    int n = g*512 + jt*16 + (lane & 15);
    int k = kt*32 + (lane >> 4)*8 + j;
    float v = (k < 64) ? Wih[n*64 + k] : Whh[n*512 + (k - 64)];
    Wp[idx] = (f16)v;
}

__global__ void pack_w2(const float* __restrict__ Wih, const float* __restrict__ Whh,
                        f16* __restrict__ Wp) {
    int idx = blockIdx.x * 256 + threadIdx.x;
    if (idx >= 4*32*32*512) return;
    int j    = idx & 7;
    int lane = (idx >> 3) & 63;
    int kt   = (idx >> 9) & 31;
    int r    = idx >> 14;
    int jt   = r & 31;
    int g    = r >> 5;
    int n = g*512 + jt*16 + (lane & 15);
    int k = kt*32 + (lane >> 4)*8 + j;
    float v = (k < 512) ? Wih[n*512 + k] : Whh[n*512 + (k - 512)];
    Wp[idx] = (f16)v;
}

__global__ void pack_wo(const float* __restrict__ Wout, f16* __restrict__ Wp) {
    int idx = blockIdx.x * 256 + threadIdx.x;
    if (idx >= 4*16*512) return;
    int j    = idx & 7;
    int lane = (idx >> 3) & 63;
    int kt   = (idx >> 9) & 15;
    int nt   = idx >> 13;
    int n = nt*16 + (lane & 15);
    int k = kt*32 + (lane >> 4)*8 + j;
    Wp[idx] = (f16)Wout[n*512 + k];
}

__global__ void bias_sum(const float* __restrict__ a1, const float* __restrict__ b1,
                         const float* __restrict__ a2, const float* __restrict__ b2,
                         float* __restrict__ s1, float* __restrict__ s2) {
    int i = blockIdx.x * 256 + threadIdx.x;
    if (i >= 2048) return;
    s1[i] = a1[i] + b1[i];
    s2[i] = a2[i] + b2[i];
}

// ---------------- persistent self-timed kernel ----------------
// R16 = R15 (rings + h1 prefetch-verify, 4337 us) + L2 loop re-schedule:
//  - pass A for t2+1 moved into the TAIL of t2, between the h1 commit and the
//    h2 ring poll: it depends only on H1W (just committed), so it now executes
//    inside the window where peer WGs are still publishing h2[t2]. Pass A
//    leaves the observe->publish critical path; the poll finds data round-1
//    more often. Costs one extra barrier (commit -> passA ordering).
//  - h1 early-issue moved to loop top (shadow extended by pass B; commit is
//    wait-free by the time it runs).
// Slot safety unchanged: loop-top loads of slot (t2+1)&7 cannot race L1's next
// write to it (that write requires a2[t2+1], which fires an iteration later);
// warm-up tag misses hit the existing fallback re-poll.
__global__ __launch_bounds__(512, 1) void lstm_persist(
    const float* __restrict__ x,
    const f16*  __restrict__ W1p,
    const f16*  __restrict__ W2p,
    const f16*  __restrict__ Wop,
    const float* __restrict__ bs1,
    const float* __restrict__ bs2,
    const float* __restrict__ bout,
    u64*  __restrict__ h1w,     // [8][2][6144] tagged words (system copy)
    u64*  __restrict__ h2w,     // [8][2][6144] (system copy)
    u64*  __restrict__ hring,   // [4 rings][8][6144] ring-local copies
    float* __restrict__ y,
    u32*  __restrict__ arr2,    // [2][1024]
    u32*  __restrict__ arrH,    // [2][1024]
    u32*  __restrict__ ctrl)    // claim/ring-init control block
{
    __shared__ __align__(16) char smem[158720];
    __shared__ int s_role, s_coh;
    float* RED = (float*)(smem + RED_OFF);
    float* CC  = (float*)(smem + CC_OFF);

    const int tid  = threadIdx.x;
    const int lane = tid & 63;
    const int w    = tid >> 6;
    const int col  = lane & 15;
    const int quad = lane >> 4;

    // ---- role claim (tid 0) ----
    u32 xcd;
    asm volatile("s_getreg_b32 %0, hwreg(HW_REG_XCC_ID)" : "=s"(xcd));
    xcd &= 7u;
    if (tid == 0) {
        u32* cnt     = ctrl;          // [8]
        u32* claimed = ctrl + 8;      // [1]
        u32* taken   = ctrl + 16;     // [130]
        u32* mx      = ctrl + 160;    // [128] member xcd+1
        u32* rcnt    = ctrl + 288;    // [4]
        int role = -1;
        u32 rank = __hip_atomic_fetch_add(&cnt[xcd], 1u, __ATOMIC_RELAXED, __HIP_MEMORY_SCOPE_AGENT);
        int pref = -1;
        if (xcd < 4u)       { if (rank < 32u) pref = (int)(xcd*32u + rank); }
        else if (xcd == 4u) { if (rank < 2u)  pref = 128 + (int)rank; }
        if (pref >= 0) {
            u32 e0 = 0;
            if (__hip_atomic_compare_exchange_strong(&taken[pref], &e0, 1u,
                    __ATOMIC_RELAXED, __ATOMIC_RELAXED, __HIP_MEMORY_SCOPE_AGENT))
                role = pref;
        }
        if (role < 0) {
            if (pref < 0)   // courtesy delay so preferred owners claim first
                for (int s = 0; s < 100; ++s) __builtin_amdgcn_s_sleep(64);
            while (role < 0) {
                if (__hip_atomic_load(claimed, __ATOMIC_RELAXED, __HIP_MEMORY_SCOPE_AGENT) >= (u32)NROLE)
                    break;
                for (int r = 0; r < NROLE; ++r) {
                    u32 e0 = 0;
                    if (__hip_atomic_load(&taken[r], __ATOMIC_RELAXED, __HIP_MEMORY_SCOPE_AGENT) == 0u &&
                        __hip_atomic_compare_exchange_strong(&taken[r], &e0, 1u,
                            __ATOMIC_RELAXED, __ATOMIC_RELAXED, __HIP_MEMORY_SCOPE_AGENT)) {
                        role = r; break;
                    }
                }
            }
        }
        int coh = 0;
        if (role >= 0) {
            __hip_atomic_fetch_add(claimed, 1u, __ATOMIC_RELAXED, __HIP_MEMORY_SCOPE_AGENT);
            if (role < 128) {   // ring member: exchange XCDs, check coherence
                const int ring = role >> 5;
                __hip_atomic_store(&mx[role], xcd + 1u, __ATOMIC_RELAXED, __HIP_MEMORY_SCOPE_AGENT);
                __hip_atomic_fetch_add(&rcnt[ring], 1u, __ATOMIC_RELEASE, __HIP_MEMORY_SCOPE_AGENT);
                while (__hip_atomic_load(&rcnt[ring], __ATOMIC_ACQUIRE, __HIP_MEMORY_SCOPE_AGENT) < 32u)
                    __builtin_amdgcn_s_sleep(1);
                coh = 1;
                u32 x0 = __hip_atomic_load(&mx[ring*32], __ATOMIC_RELAXED, __HIP_MEMORY_SCOPE_AGENT);
                for (int i = 1; i < 32; ++i)
                    if (__hip_atomic_load(&mx[ring*32 + i], __ATOMIC_RELAXED, __HIP_MEMORY_SCOPE_AGENT) != x0)
                        coh = 0;
            }
        }
        s_role = role;
        s_coh  = coh;
    }
    __syncthreads();
    const int role = s_role;
    const int coh  = s_coh;
    if (role < 0) return;

    // staging LDS offsets for this thread's 12 words
    int soff[12];
    #pragma unroll
    for (int i = 0; i < 12; ++i) {
        const int ww = i*512 + tid;
        const int jt_ = ww / 192, rr = ww - jt_*192;
        soff[i] = WB(jt_, rr/6, rr%6);
    }
    // publisher params (valid for tid<192): word tid = r*6 + i of own slice
    const int pr  = tid / 6, pi = tid - pr*6;
    const int pj  = pi % 3;
    const int pc0 = pr*16 + (pi/3)*8 + pj*3;
    const u16* hb = (const u16*)(smem + HB_OFF);

    if (role < 64) {
        // ================= layer 1 =================
        const int bhalf = role >> 5, jt = role & 31;
        u64* rbuf = hring + (size_t)bhalf * RSLOT;      // ring 0/1
        int* esc  = (int*)(smem + H2W_OFF);             // L1 never uses H2W
        if (tid == 0) *esc = 0;
        const int gp = w & 1, kq = w >> 1;
        half8 wrx[2];
        half8 wrh[2][4];
        if (kq < 2) {
            #pragma unroll
            for (int gi = 0; gi < 2; ++gi)
                wrx[gi] = *(const half8*)(W1p + ((size_t)(((gp*2+gi)*32 + jt)*18 + kq)*64 + lane)*8);
        }
        #pragma unroll
        for (int gi = 0; gi < 2; ++gi)
            #pragma unroll
            for (int k = 0; k < 4; ++k) {
                const int kt = 2 + kq*4 + k;
                wrh[gi][k] = *(const half8*)(W1p + ((size_t)(((gp*2+gi)*32 + jt)*18 + kt)*64 + lane)*8);
            }
        float bsr[4];
        #pragma unroll
        for (int g = 0; g < 4; ++g) bsr[g] = bs1[g*512 + jt*16 + (tid & 15)];
        CC[tid] = 0.f;

        u32* a2 = arr2 + bhalf*1024;
        const int lbx = tid >> 4, kcx = tid & 15;
        const float* xbase = x + (size_t)(bhalf*32 + lbx)*T_*(size_t)IN_ + ((kcx ^ (lbx & 7)) * 4);

        // prologue: x_0 + h1[-1] (slot 7, tag 0 = zeroed buffers)
        *(float4*)(smem + XS_OFF + tid*16) = *(const float4*)xbase;
        __syncthreads();   // esc visible
        stage_poll_r(smem, H1W_OFF, rbuf + (size_t)7*NWORD,
                     h1w + (size_t)(7*2 + bhalf)*NWORD, 0u, tid, soff, coh, esc);
        __syncthreads();

        for (int t = 0; t < T_; ++t) {
            float4 xreg;
            if (t + 1 < T_) xreg = *(const float4*)(xbase + (size_t)(t+1)*IN_);

            floatx4 acc[2][2] = {{{0.f,0.f,0.f,0.f},{0.f,0.f,0.f,0.f}},
                                 {{0.f,0.f,0.f,0.f},{0.f,0.f,0.f,0.f}}};
            #pragma unroll
            for (int m = 0; m < 2; ++m) {
                const int lb_a = m*16 + col, sw = lb_a & 7;
                if (kq < 2) {
                    const int fg = kq*8 + quad*2;
                    float4 u = *(const float4*)(smem + XS_OFF + ((size_t)lb_a*16 + (fg ^ sw))*16);
                    float4 v = *(const float4*)(smem + XS_OFF + ((size_t)lb_a*16 + ((fg+1) ^ sw))*16);
                    half8 a = (half8){(f16)u.x,(f16)u.y,(f16)u.z,(f16)u.w,
                                      (f16)v.x,(f16)v.y,(f16)v.z,(f16)v.w};
                    acc[0][m] = MFMA16(a, wrx[0], acc[0][m]);
                    acc[1][m] = MFMA16(a, wrx[1], acc[1][m]);
                }
                #pragma unroll
                for (int k = 0; k < 4; ++k) {
                    const int kc = kq*16 + k*4 + quad;
                    half8 a = frag_pk(smem + H1W_OFF + WB(kc>>1, lb_a, (kc&1)*3));
                    acc[0][m] = MFMA16(a, wrh[0][k], acc[0][m]);
                    acc[1][m] = MFMA16(a, wrh[1][k], acc[1][m]);
                }
            }
            #pragma unroll
            for (int gi = 0; gi < 2; ++gi) {
                const int g = gp*2 + gi;
                #pragma unroll
                for (int m = 0; m < 2; ++m)
                    #pragma unroll
                    for (int r = 0; r < 4; ++r)
                        RED[kq*2048 + g*512 + (m*16 + quad*4 + r)*16 + col] = acc[gi][m][r];
            }
            __syncthreads();
            {   // 4-way kq sum + pointwise -> HB
                float gt[4];
                #pragma unroll
                for (int g = 0; g < 4; ++g)
                    gt[g] = RED[       g*512 + tid] + RED[2048 + g*512 + tid]
                          + RED[4096 + g*512 + tid] + RED[6144 + g*512 + tid] + bsr[g];
                const float i_ = sigmoidf_(gt[0]);
                const float f_ = sigmoidf_(gt[1]);
                const float g_ = tanhf_(gt[2]);
                const float o_ = sigmoidf_(gt[3]);
                const float cn = f_ * CC[tid] + i_ * g_;
                CC[tid] = cn;
                ((f16*)(smem + HB_OFF))[tid] = (f16)(o_ * tanhf_(cn));
            }
            __syncthreads();
            // publish h1[t]: system copy always (L2 consumes); ring copy if coherent
            if (tid < 192) {
                u64 wv = (u64)hb[pc0] | ((u64)hb[pc0+1] << 16)
                       | ((pj < 2) ? ((u64)hb[pc0+2] << 32) : 0)
                       | ((u64)(u32)(t + 1) << 48);
                astore8w(h1w + (size_t)((t & 7)*2 + bhalf)*NWORD + jt*192 + tid, wv);
                if (coh) astore8a(rbuf + (size_t)(t & 7)*NWORD + jt*192 + tid, wv);
            }
            const bool needA2 = (tid == 0) && (t + 1 < T_) && (t + 1 >= SLOTS);
            u32 fA2 = needA2 ? flag_peek(a2 + (t + 1 - SLOTS)) : 32u;
            if (t + 1 < T_) {
                *(float4*)(smem + XS_OFF + tid*16) = xreg;
                stage_poll_r(smem, H1W_OFF, rbuf + (size_t)(t & 7)*NWORD,
                             h1w + (size_t)((t & 7)*2 + bhalf)*NWORD,
                             (u32)(t + 1), tid, soff, coh, esc);
            }
            if (needA2 && fA2 < 32u) wait_ge(a2 + (t + 1 - SLOTS), 32u);
            __syncthreads();
        }
    } else if (role < 128) {
        // ================= layer 2 =================
        const int v = role - 64;
        const int bhalf = v >> 5, jt = v & 31;
        u64* rbuf = hring + (size_t)(2 + bhalf) * RSLOT;   // ring 2/3
        int* esc  = (int*)(smem + XS_OFF);                 // L2 never uses XS
        if (tid == 0) *esc = 0;
        const int gp = w & 1, kq = w >> 1;
        half8 wrA[2][4], wrB[2][4];
        #pragma unroll
        for (int gi = 0; gi < 2; ++gi)
            #pragma unroll
            for (int k = 0; k < 4; ++k) {
                const int ktA = kq*4 + k;
                const int ktB = 16 + kq*4 + k;
                wrA[gi][k] = *(const half8*)(W2p + ((size_t)(((gp*2+gi)*32 + jt)*32 + ktA)*64 + lane)*8);
                wrB[gi][k] = *(const half8*)(W2p + ((size_t)(((gp*2+gi)*32 + jt)*32 + ktB)*64 + lane)*8);
            }
        float bsr[4];
        #pragma unroll
        for (int g = 0; g < 4; ++g) bsr[g] = bs2[g*512 + jt*16 + (tid & 15)];
        CC[tid] = 0.f;

        u32* a2 = arr2 + bhalf*1024;
        u32* aH = arrH + bhalf*1024;

        // prologue: h1[0] (system, tag 1) then h2[-1] (ring/system, slot 7 tag 0)
        __syncthreads();   // esc visible
        stage_poll(smem, H1W_OFF, h1w + (size_t)(0*2 + bhalf)*NWORD, 1u, tid, soff);
        stage_poll_r(smem, H2W_OFF, rbuf + (size_t)7*NWORD,
                     h2w + (size_t)(7*2 + bhalf)*NWORD, 0u, tid, soff, coh, esc);
        __syncthreads();

        floatx4 acc[2][2];
        // pass A for t2=0 (h1[0] from H1W)
        #pragma unroll
        for (int gi = 0; gi < 2; ++gi)
            #pragma unroll
            for (int m = 0; m < 2; ++m)
                acc[gi][m] = (floatx4){0.f,0.f,0.f,0.f};
        #pragma unroll
        for (int m = 0; m < 2; ++m) {
            const int lb_a = m*16 + col;
            #pragma unroll
            for (int k = 0; k < 4; ++k) {
                const int kc = kq*16 + k*4 + quad;
                half8 a = frag_pk(smem + H1W_OFF + WB(kc>>1, lb_a, (kc&1)*3));
                acc[0][m] = MFMA16(a, wrA[0][k], acc[0][m]);
                acc[1][m] = MFMA16(a, wrA[1][k], acc[1][m]);
            }
        }

        for (int t2 = 0; t2 < T_; ++t2) {
            // EARLY ISSUE (loop top): h1[t2+1] system loads -> registers. The
            // MALL RT hides under pass B + RED + pointwise + publish; the tail
            // commit is wait-free by then.
            u64 h1r[12];
            const u64* g1n = h1w + (size_t)(((t2+1) & 7)*2 + bhalf)*NWORD;
            if (t2 + 1 < T_) {
                #pragma unroll
                for (int i = 0; i < 12; ++i) h1r[i] = aload8w(g1n + i*512 + tid);
            }
            // ---- pass B (h2[t2-1]) -- completes the gates (pass A ran in the
            // previous tail / prologue) ----
            #pragma unroll
            for (int m = 0; m < 2; ++m) {
                const int lb_a = m*16 + col;
                #pragma unroll
                for (int k = 0; k < 4; ++k) {
                    const int kc = kq*16 + k*4 + quad;
                    half8 a = frag_pk(smem + H2W_OFF + WB(kc>>1, lb_a, (kc&1)*3));
                    acc[0][m] = MFMA16(a, wrB[0][k], acc[0][m]);
                    acc[1][m] = MFMA16(a, wrB[1][k], acc[1][m]);
                }
            }
            #pragma unroll
            for (int gi = 0; gi < 2; ++gi) {
                const int g = gp*2 + gi;
                #pragma unroll
                for (int m = 0; m < 2; ++m)
                    #pragma unroll
                    for (int r = 0; r < 4; ++r)
                        RED[kq*2048 + g*512 + (m*16 + quad*4 + r)*16 + col] = acc[gi][m][r];
            }
            __syncthreads();
            {   // 4-way kq sum + pointwise -> HB
                float gt[4];
                #pragma unroll
                for (int g = 0; g < 4; ++g)
                    gt[g] = RED[       g*512 + tid] + RED[2048 + g*512 + tid]
                          + RED[4096 + g*512 + tid] + RED[6144 + g*512 + tid] + bsr[g];
                const float i_ = sigmoidf_(gt[0]);
                const float f_ = sigmoidf_(gt[1]);
                const float g_ = tanhf_(gt[2]);
                const float o_ = sigmoidf_(gt[3]);
                const float cn = f_ * CC[tid] + i_ * g_;
                CC[tid] = cn;
                ((f16*)(smem + HB_OFF))[tid] = (f16)(o_ * tanhf_(cn));
            }
            __syncthreads();
            // publish h2[t2]: system copy always (head consumes); ring copy if coherent
            if (tid < 192) {
                u64 wv = (u64)hb[pc0] | ((u64)hb[pc0+1] << 16)
                       | ((pj < 2) ? ((u64)hb[pc0+2] << 32) : 0)
                       | ((u64)(u32)(t2 + 1) << 48);
                astore8w(h2w + (size_t)((t2 & 7)*2 + bhalf)*NWORD + jt*192 + tid, wv);
                if (coh) astore8a(rbuf + (size_t)(t2 & 7)*NWORD + jt*192 + tid, wv);
            }
            if (tid == 0) flag_add(a2 + t2);
            const bool needAH = (tid == 0) && (t2 + 1 < T_) && (t2 + 1 >= SLOTS);
            u32 fAH = needAH ? flag_peek(aH + (t2 + 1 - SLOTS)) : 1u;
            if (t2 + 1 < T_) {
                // commit h1[t2+1] (loads issued at loop top; returned long ago)
                u32 pend = 0xFFFu;
                #pragma unroll
                for (int i = 0; i < 12; ++i) {
                    if ((u32)(h1r[i] >> 48) == (u32)(t2 + 2)) {
                        *(u64*)(smem + H1W_OFF + soff[i]) = h1r[i];
                        pend &= ~(1u << i);
                    }
                }
                while (pend) {   // rare (warm-up): straggler re-poll
                    u64 vv[12];
                    #pragma unroll
                    for (int i = 0; i < 12; ++i) vv[i] = aload8w(g1n + i*512 + tid);
                    #pragma unroll
                    for (int i = 0; i < 12; ++i) {
                        if ((pend & (1u << i)) && (u32)(vv[i] >> 48) == (u32)(t2 + 2)) {
                            *(u64*)(smem + H1W_OFF + soff[i]) = vv[i];
                            pend &= ~(1u << i);
                        }
                    }
                    if (pend) __builtin_amdgcn_s_sleep(1);
                }
                __syncthreads();   // H1W committed -> pass A may read
                // ---- pass A for t2+1: runs inside the peer-publish skew
                // window, off the observe->publish critical path ----
                #pragma unroll
                for (int gi = 0; gi < 2; ++gi)
                    #pragma unroll
                    for (int m = 0; m < 2; ++m)
                        acc[gi][m] = (floatx4){0.f,0.f,0.f,0.f};
                #pragma unroll
                for (int m = 0; m < 2; ++m) {
                    const int lb_a = m*16 + col;
                    #pragma unroll
                    for (int k = 0; k < 4; ++k) {
                        const int kc = kq*16 + k*4 + quad;
                        half8 a = frag_pk(smem + H1W_OFF + WB(kc>>1, lb_a, (kc&1)*3));
                        acc[0][m] = MFMA16(a, wrA[0][k], acc[0][m]);
                        acc[1][m] = MFMA16(a, wrA[1][k], acc[1][m]);
                    }
                }
                // live edge: h2[t2] ring poll
                stage_poll_r(smem, H2W_OFF, rbuf + (size_t)(t2 & 7)*NWORD,
                             h2w + (size_t)((t2 & 7)*2 + bhalf)*NWORD,
                             (u32)(t2 + 1), tid, soff, coh, esc);
            }
            if (needAH && fAH < 1u) wait_ge(aH + (t2 + 1 - SLOTS), 1u);
            __syncthreads();
        }
    } else {
        // ================= head =================
        const int bhalf = role - 128;
        const int nt = w & 3, kh = w >> 2;
        half8 wr[8];
        #pragma unroll
        for (int k = 0; k < 8; ++k) {
            const int kt = kh*8 + k;
            wr[k] = *(const half8*)(Wop + ((size_t)(nt*16 + kt)*64 + lane)*8);
        }
        const float boutr = bout[nt*16 + col];
        u32* aH = arrH + bhalf*1024;
        const int lb0 = col, lb1 = 16 + col;

        stage_poll(smem, H1W_OFF, h2w + (size_t)(0*2 + bhalf)*NWORD, 1u, tid, soff);
        __syncthreads();
        if (tid == 0) flag_add(aH + 0);

        for (int t3 = 0; t3 < T_; ++t3) {
            floatx4 acc0 = {0.f,0.f,0.f,0.f}, acc1 = {0.f,0.f,0.f,0.f};
            #pragma unroll
            for (int k = 0; k < 8; ++k) {
                const int kc = (kh*8 + k)*4 + quad;
                half8 a0  = frag_pk(smem + H1W_OFF + WB(kc>>1, lb0, (kc&1)*3));
                half8 a1v = frag_pk(smem + H1W_OFF + WB(kc>>1, lb1, (kc&1)*3));
                acc0 = MFMA16(a0,  wr[k], acc0);
                acc1 = MFMA16(a1v, wr[k], acc1);
            }
            if (kh == 1) {
                #pragma unroll
                for (int r = 0; r < 4; ++r) {
                    RED[(nt*2+0)*256 + (quad*4 + r)*16 + col] = acc0[r];
                    RED[(nt*2+1)*256 + (quad*4 + r)*16 + col] = acc1[r];
                }
            }
            __syncthreads();
            if (kh == 0) {
                #pragma unroll
                for (int r = 0; r < 4; ++r) {
                    const float v0 = acc0[r] + RED[(nt*2+0)*256 + (quad*4 + r)*16 + col] + boutr;
                    const float v1 = acc1[r] + RED[(nt*2+1)*256 + (quad*4 + r)*16 + col] + boutr;
                    const int b0 = bhalf*32 +  0 + quad*4 + r;
                    const int b1 = bhalf*32 + 16 + quad*4 + r;
                    y[((size_t)b0*T_ + t3)*OUT_ + nt*16 + col] = v0;
                    y[((size_t)b1*T_ + t3)*OUT_ + nt*16 + col] = v1;
                }
            }
            __syncthreads();
            if (t3 + 1 < T_) {
                stage_poll(smem, H1W_OFF, h2w + (size_t)(((t3+1) & 7)*2 + bhalf)*NWORD,
                           (u32)(t3 + 2), tid, soff);
                __syncthreads();
                if (tid == 0) flag_add(aH + (t3 + 1));
            }
        }
    }
}

// ---------------- launch ----------------
extern "C" void kernel_launch(void* const* d_in, const int* in_sizes, int n_in,
                              void* d_out, int out_size, void* d_ws, size_t ws_size,
                              hipStream_t stream) {
    const float* x    = (const float*)d_in[0];
    const float* Wih1 = (const float*)d_in[1];
    const float* Whh1 = (const float*)d_in[2];
    const float* bih1 = (const float*)d_in[3];
    const float* bhh1 = (const float*)d_in[4];
    const float* Wih2 = (const float*)d_in[5];
    const float* Whh2 = (const float*)d_in[6];
    const float* bih2 = (const float*)d_in[7];
    const float* bhh2 = (const float*)d_in[8];
    const float* Wout = (const float*)d_in[9];
    const float* bout = (const float*)d_in[10];
    float* y = (float*)d_out;

    char* ws = (char*)d_ws;
    f16*   W1p   = (f16*)(ws + 0);           // 2,359,296 B
    f16*   W2p   = (f16*)(ws + 2359296);     // 4,194,304 B
    f16*   Wop   = (f16*)(ws + 6553600);     //    65,536 B
    float* bs1   = (float*)(ws + 6619136);   //     8,192 B
    float* bs2   = (float*)(ws + 6627328);   //     8,192 B
    u64*   h1w   = (u64*)(ws + 6635520);     //   786,432 B
    u64*   h2w   = (u64*)(ws + 7421952);     //   786,432 B
    u32*   arr2  = (u32*)(ws + 8208384);     //     8,192 B
    u32*   arrH  = (u32*)(ws + 8216576);     //     8,192 B
    u64*   hring = (u64*)(ws + 8224768);     // 1,572,864 B (4 rings x 8 slots)
    u32*   ctrl  = (u32*)(ws + 9797632);     //     1,168 B

    // zero tagged buffers (tag 0 = step -1 state), counters, rings, ctrl
    hipMemsetAsync(ws + 6635520, 0, 3163280, stream);

    pack_w1<<<4608, 256, 0, stream>>>(Wih1, Whh1, W1p);
    pack_w2<<<8192, 256, 0, stream>>>(Wih2, Whh2, W2p);
    pack_wo<<<128, 256, 0, stream>>>(Wout, Wop);
    bias_sum<<<8, 256, 0, stream>>>(bih1, bhh1, bih2, bhh2, bs1, bs2);

    lstm_persist<<<NWG, 512, 0, stream>>>(x, W1p, W2p, Wop, bs1, bs2, bout,
                                          h1w, h2w, hring, y, arr2, arrH, ctrl);
}

// Round 12
// 4196.796 us; speedup vs baseline: 1.1048x; 1.1048x over previous
//
#include <hip/hip_runtime.h>

#define B_    64
#define T_    1024
#define IN_   64
#define H_    512
#define OUT_  64
#define SLOTS 8
#define NWG   256
#define NROLE 130
#define NWORD 6144      // words per (bhalf, slot): 32 jt * 32 rows * 6 words
#define RSLOT (8*NWORD) // words per ring (8 slots)

typedef _Float16 f16;
typedef _Float16 half8 __attribute__((ext_vector_type(8)));
typedef float    floatx4 __attribute__((ext_vector_type(4)));
typedef unsigned int u32;
typedef unsigned short u16;
typedef unsigned long long u64;

#define MFMA16(a,b,c) __builtin_amdgcn_mfma_f32_16x16x32_f16((a),(b),(c),0,0,0)

// LDS layout (158720 B, 1 WG/CU)
#define XS_OFF   0        // 8KB: L1 x-stage (L2 reuses first 4B as esc flag)
#define HB_OFF   8192     // 1KB: pointwise h output (f16[512])
#define CC_OFF   9216     // 2KB: c-state
#define RED_OFF  11264    // 32KB: 4 kq-regions x 8KB partial-sum
#define H1W_OFF  44032    // 57344: packed h words (h1 for L1/L2; h2 for head)
#define H2W_OFF  101376   // 57344: packed h2 words (L2 pass B; L1 reuses first 4B as esc)

__device__ __forceinline__ float sigmoidf_(float x) {
    return 1.0f / (1.0f + __expf(-x));
}
__device__ __forceinline__ float tanhf_(float x) {
    float ax = fabsf(x);
    float e  = __expf(-2.0f * ax);
    float t  = (1.0f - e) / (1.0f + e);
    return x >= 0.0f ? t : -t;
}

// R17 core: lgkm-only barrier. __syncthreads() drains vmcnt(0) -- which
// serializes the system-publish store ACKS (~1us MALL RT) and any in-flight
// register prefetch loads into every loop barrier. All in-loop visibility
// requirements are LDS-only (RED / HB / staged H1W / H2W), so
// lgkmcnt(0) + s_barrier suffices. vmem consumers keep their natural
// per-use waits (tag-check waits on its own loads; store acks NEVER waited).
// sched_barrier(0) fences compiler hoisting past the asm waitcnt (rule #18).
__device__ __forceinline__ void barrier_lds() {
    asm volatile("s_waitcnt lgkmcnt(0)" ::: "memory");
    __builtin_amdgcn_s_barrier();
    __builtin_amdgcn_sched_barrier(0);
}

// Flags: agent-scope RMW + agent-scope poll (proven R2/R5). Back-pressure edges only.
__device__ __forceinline__ u32 flag_peek(const u32* p) {
    return __hip_atomic_load(p, __ATOMIC_RELAXED, __HIP_MEMORY_SCOPE_AGENT);
}
__device__ __forceinline__ void wait_ge(u32* p, u32 v) {
    while (__hip_atomic_load(p, __ATOMIC_RELAXED, __HIP_MEMORY_SCOPE_AGENT) < v)
        __builtin_amdgcn_s_sleep(1);
}
__device__ __forceinline__ void flag_add(u32* p) {
    __hip_atomic_fetch_add(p, 1u, __ATOMIC_RELAXED, __HIP_MEMORY_SCOPE_AGENT);
}
// System-scope tagged-word ops (MALL coherence point) -- cross-XCD edges. Proven R9.
__device__ __forceinline__ void astore8w(u64* p, u64 v) {
    __hip_atomic_store(p, v, __ATOMIC_RELAXED, __HIP_MEMORY_SCOPE_SYSTEM);
}
__device__ __forceinline__ u64 aload8w(const u64* p) {
    return __hip_atomic_load(p, __ATOMIC_RELAXED, __HIP_MEMORY_SCOPE_SYSTEM);
}
// Agent-scope tagged-word ops -- intra-XCD ring edges (shared XCD L2 is the
// physical coherence point when all ring members sit on one XCD). Proven R14
// (FETCH_SIZE 866->215 MB).
__device__ __forceinline__ void astore8a(u64* p, u64 v) {
    __hip_atomic_store(p, v, __ATOMIC_RELAXED, __HIP_MEMORY_SCOPE_AGENT);
}
__device__ __forceinline__ u64 aload8a(const u64* p) {
    return __hip_atomic_load(p, __ATOMIC_RELAXED, __HIP_MEMORY_SCOPE_AGENT);
}

// Poll-stage ONE 49KB tagged buffer (6144 words) into LDS. 12-load rounds (R11
// lesson: never widen rounds).
__device__ __forceinline__ void stage_poll(char* smem, int ldsOff, const u64* g,
                                           u32 exp, int tid, const int* soff) {
    u32 pend = 0xFFFu;
    do {
        u64 vv[12];
        #pragma unroll
        for (int i = 0; i < 12; ++i)
            vv[i] = aload8w(g + i*512 + tid);
        #pragma unroll
        for (int i = 0; i < 12; ++i) {
            if ((pend & (1u << i)) && (u32)(vv[i] >> 48) == exp) {
                *(u64*)(smem + ldsOff + soff[i]) = vv[i];
                pend &= ~(1u << i);
            }
        }
        if (pend) __builtin_amdgcn_s_sleep(1);
    } while (pend);
}

// Ring poll: agent-scope loads from the ring copy (gr) when the ring is
// XCD-coherent; system loads from the always-published system copy (gs) when
// not, or after a sticky escape (safety: completes even if agent semantics
// differ from the hypothesis -- at R9 speed, never wrong, never hung).
__device__ __forceinline__ void stage_poll_r(char* smem, int ldsOff,
                                             const u64* gr, const u64* gs,
                                             u32 exp, int tid, const int* soff,
                                             int coh, int* esc) {
    u32 pend = 0xFFFu;
    int rounds = 0;
    bool useSys = (!coh) || (*esc != 0);
    do {
        u64 vv[12];
        if (!useSys) {
            #pragma unroll
            for (int i = 0; i < 12; ++i) vv[i] = aload8a(gr + i*512 + tid);
        } else {
            #pragma unroll
            for (int i = 0; i < 12; ++i) vv[i] = aload8w(gs + i*512 + tid);
        }
        #pragma unroll
        for (int i = 0; i < 12; ++i) {
            if ((pend & (1u << i)) && (u32)(vv[i] >> 48) == exp) {
                *(u64*)(smem + ldsOff + soff[i]) = vv[i];
                pend &= ~(1u << i);
            }
        }
        if (pend) {
            __builtin_amdgcn_s_sleep(1);
            if (!useSys && ++rounds >= 1024) { useSys = true; *esc = 1; }
        }
    } while (pend);
}

// Build a half8 fragment (8 consecutive k-values) from 3 packed LDS words.
__device__ __forceinline__ half8 frag_pk(const char* p) {
    const u64* q = (const u64*)p;
    u64 w0 = q[0], w1 = q[1], w2 = q[2];
    u32 b = (u32)(w0 >> 32), c = (u32)w1, d = (u32)(w1 >> 32);
    union { u32 u[4]; half8 h; } U;
    U.u[0] = (u32)w0;
    U.u[1] = (b & 0xffffu) | (c << 16);
    U.u[2] = (c >> 16) | (d << 16);
    U.u[3] = (u32)w2;
    return U.h;
}
// LDS byte offset of word (jt, row, wi): ((jt*32+row)*7 + wi)*8
#define WB(jt,row,wi) (((jt)*224 + (row)*7 + (wi)) * 8)

// ---------------- prep kernels (weights -> fp16 fragment-linear) ----------------
__global__ void pack_w1(const float* __restrict__ Wih, const float* __restrict__ Whh,
                        f16* __restrict__ Wp) {
    int idx = blockIdx.x * 256 + threadIdx.x;
    if (idx >= 4*32*18*512) return;
    int j    = idx & 7;
    int lane = (idx >> 3) & 63;
    int kt   = (idx >> 9) % 18;
    int r    = (idx >> 9) / 18;
    int jt   = r & 31;
    int g    = r >> 5;
    int n = g*512 + jt*16 + (lane & 15);
    int k = kt*32 + (lane >> 4)*8 + j;
    float v = (k < 64) ? Wih[n*64 + k] : Whh[n*512 + (k - 64)];
    Wp[idx] = (f16)v;
}

__global__ void pack_w2(const float* __restrict__ Wih, const float* __restrict__ Whh,
                        f16* __restrict__ Wp) {
    int idx = blockIdx.x * 256 + threadIdx.x;
    if (idx >= 4*32*32*512) return;
    int j    = idx & 7;
    int lane = (idx >> 3) & 63;
    int kt   = (idx >> 9) & 31;
    int r    = idx >> 14;
    int jt   = r & 31;
    int g    = r >> 5;
    int n = g*512 + jt*16 + (lane & 15);
    int k = kt*32 + (lane >> 4)*8 + j;
    float v = (k < 512) ? Wih[n*512 + k] : Whh[n*512 + (k - 512)];
    Wp[idx] = (f16)v;
}

__global__ void pack_wo(const float* __restrict__ Wout, f16* __restrict__ Wp) {
    int idx = blockIdx.x * 256 + threadIdx.x;
    if (idx >= 4*16*512) return;
    int j    = idx & 7;
    int lane = (idx >> 3) & 63;
    int kt   = (idx >> 9) & 15;
    int nt   = idx >> 13;
    int n = nt*16 + (lane & 15);
    int k = kt*32 + (lane >> 4)*8 + j;
    Wp[idx] = (f16)Wout[n*512 + k];
}

__global__ void bias_sum(const float* __restrict__ a1, const float* __restrict__ b1,
                         const float* __restrict__ a2, const float* __restrict__ b2,
                         float* __restrict__ s1, float* __restrict__ s2) {
    int i = blockIdx.x * 256 + threadIdx.x;
    if (i >= 2048) return;
    s1[i] = a1[i] + b1[i];
    s2[i] = a2[i] + b2[i];
}

// ---------------- persistent self-timed kernel ----------------
// R17 = R15 structure verbatim (rings + loop-top h1 prefetch-verify; best
// 4337 us; R16's pass-A move reverted) + ONE change: all in-loop
// __syncthreads() -> barrier_lds() (lgkmcnt-only). The publish store acks and
// in-flight h1 prefetch loads no longer drain into every barrier.
__global__ __launch_bounds__(512, 1) void lstm_persist(
    const float* __restrict__ x,
    const f16*  __restrict__ W1p,
    const f16*  __restrict__ W2p,
    const f16*  __restrict__ Wop,
    const float* __restrict__ bs1,
    const float* __restrict__ bs2,
    const float* __restrict__ bout,
    u64*  __restrict__ h1w,     // [8][2][6144] tagged words (system copy)
    u64*  __restrict__ h2w,     // [8][2][6144] (system copy)
    u64*  __restrict__ hring,   // [4 rings][8][6144] ring-local copies
    float* __restrict__ y,
    u32*  __restrict__ arr2,    // [2][1024]
    u32*  __restrict__ arrH,    // [2][1024]
    u32*  __restrict__ ctrl)    // claim/ring-init control block
{
    __shared__ __align__(16) char smem[158720];
    __shared__ int s_role, s_coh;
    float* RED = (float*)(smem + RED_OFF);
    float* CC  = (float*)(smem + CC_OFF);

    const int tid  = threadIdx.x;
    const int lane = tid & 63;
    const int w    = tid >> 6;
    const int col  = lane & 15;
    const int quad = lane >> 4;

    // ---- role claim (tid 0) ----
    u32 xcd;
    asm volatile("s_getreg_b32 %0, hwreg(HW_REG_XCC_ID)" : "=s"(xcd));
    xcd &= 7u;
    if (tid == 0) {
        u32* cnt     = ctrl;          // [8]
        u32* claimed = ctrl + 8;      // [1]
        u32* taken   = ctrl + 16;     // [130]
        u32* mx      = ctrl + 160;    // [128] member xcd+1
        u32* rcnt    = ctrl + 288;    // [4]
        int role = -1;
        u32 rank = __hip_atomic_fetch_add(&cnt[xcd], 1u, __ATOMIC_RELAXED, __HIP_MEMORY_SCOPE_AGENT);
        int pref = -1;
        if (xcd < 4u)       { if (rank < 32u) pref = (int)(xcd*32u + rank); }
        else if (xcd == 4u) { if (rank < 2u)  pref = 128 + (int)rank; }
        if (pref >= 0) {
            u32 e0 = 0;
            if (__hip_atomic_compare_exchange_strong(&taken[pref], &e0, 1u,
                    __ATOMIC_RELAXED, __ATOMIC_RELAXED, __HIP_MEMORY_SCOPE_AGENT))
                role = pref;
        }
        if (role < 0) {
            if (pref < 0)   // courtesy delay so preferred owners claim first
                for (int s = 0; s < 100; ++s) __builtin_amdgcn_s_sleep(64);
            while (role < 0) {
                if (__hip_atomic_load(claimed, __ATOMIC_RELAXED, __HIP_MEMORY_SCOPE_AGENT) >= (u32)NROLE)
                    break;
                for (int r = 0; r < NROLE; ++r) {
                    u32 e0 = 0;
                    if (__hip_atomic_load(&taken[r], __ATOMIC_RELAXED, __HIP_MEMORY_SCOPE_AGENT) == 0u &&
                        __hip_atomic_compare_exchange_strong(&taken[r], &e0, 1u,
                            __ATOMIC_RELAXED, __ATOMIC_RELAXED, __HIP_MEMORY_SCOPE_AGENT)) {
                        role = r; break;
                    }
                }
            }
        }
        int coh = 0;
        if (role >= 0) {
            __hip_atomic_fetch_add(claimed, 1u, __ATOMIC_RELAXED, __HIP_MEMORY_SCOPE_AGENT);
            if (role < 128) {   // ring member: exchange XCDs, check coherence
                const int ring = role >> 5;
                __hip_atomic_store(&mx[role], xcd + 1u, __ATOMIC_RELAXED, __HIP_MEMORY_SCOPE_AGENT);
                __hip_atomic_fetch_add(&rcnt[ring], 1u, __ATOMIC_RELEASE, __HIP_MEMORY_SCOPE_AGENT);
                while (__hip_atomic_load(&rcnt[ring], __ATOMIC_ACQUIRE, __HIP_MEMORY_SCOPE_AGENT) < 32u)
                    __builtin_amdgcn_s_sleep(1);
                coh = 1;
                u32 x0 = __hip_atomic_load(&mx[ring*32], __ATOMIC_RELAXED, __HIP_MEMORY_SCOPE_AGENT);
                for (int i = 1; i < 32; ++i)
                    if (__hip_atomic_load(&mx[ring*32 + i], __ATOMIC_RELAXED, __HIP_MEMORY_SCOPE_AGENT) != x0)
                        coh = 0;
            }
        }
        s_role = role;
        s_coh  = coh;
    }
    __syncthreads();
    const int role = s_role;
    const int coh  = s_coh;
    if (role < 0) return;

    // staging LDS offsets for this thread's 12 words
    int soff[12];
    #pragma unroll
    for (int i = 0; i < 12; ++i) {
        const int ww = i*512 + tid;
        const int jt_ = ww / 192, rr = ww - jt_*192;
        soff[i] = WB(jt_, rr/6, rr%6);
    }
    // publisher params (valid for tid<192): word tid = r*6 + i of own slice
    const int pr  = tid / 6, pi = tid - pr*6;
    const int pj  = pi % 3;
    const int pc0 = pr*16 + (pi/3)*8 + pj*3;
    const u16* hb = (const u16*)(smem + HB_OFF);

    if (role < 64) {
        // ================= layer 1 =================
        const int bhalf = role >> 5, jt = role & 31;
        u64* rbuf = hring + (size_t)bhalf * RSLOT;      // ring 0/1
        int* esc  = (int*)(smem + H2W_OFF);             // L1 never uses H2W
        if (tid == 0) *esc = 0;
        const int gp = w & 1, kq = w >> 1;
        half8 wrx[2];
        half8 wrh[2][4];
        if (kq < 2) {
            #pragma unroll
            for (int gi = 0; gi < 2; ++gi)
                wrx[gi] = *(const half8*)(W1p + ((size_t)(((gp*2+gi)*32 + jt)*18 + kq)*64 + lane)*8);
        }
        #pragma unroll
        for (int gi = 0; gi < 2; ++gi)
            #pragma unroll
            for (int k = 0; k < 4; ++k) {
                const int kt = 2 + kq*4 + k;
                wrh[gi][k] = *(const half8*)(W1p + ((size_t)(((gp*2+gi)*32 + jt)*18 + kt)*64 + lane)*8);
            }
        float bsr[4];
        #pragma unroll
        for (int g = 0; g < 4; ++g) bsr[g] = bs1[g*512 + jt*16 + (tid & 15)];
        CC[tid] = 0.f;

        u32* a2 = arr2 + bhalf*1024;
        const int lbx = tid >> 4, kcx = tid & 15;
        const float* xbase = x + (size_t)(bhalf*32 + lbx)*T_*(size_t)IN_ + ((kcx ^ (lbx & 7)) * 4);

        // prologue: x_0 + h1[-1] (slot 7, tag 0 = zeroed buffers)
        *(float4*)(smem + XS_OFF + tid*16) = *(const float4*)xbase;
        __syncthreads();   // esc visible
        stage_poll_r(smem, H1W_OFF, rbuf + (size_t)7*NWORD,
                     h1w + (size_t)(7*2 + bhalf)*NWORD, 0u, tid, soff, coh, esc);
        __syncthreads();

        for (int t = 0; t < T_; ++t) {
            float4 xreg;
            if (t + 1 < T_) xreg = *(const float4*)(xbase + (size_t)(t+1)*IN_);

            floatx4 acc[2][2] = {{{0.f,0.f,0.f,0.f},{0.f,0.f,0.f,0.f}},
                                 {{0.f,0.f,0.f,0.f},{0.f,0.f,0.f,0.f}}};
            #pragma unroll
            for (int m = 0; m < 2; ++m) {
                const int lb_a = m*16 + col, sw = lb_a & 7;
                if (kq < 2) {
                    const int fg = kq*8 + quad*2;
                    float4 u = *(const float4*)(smem + XS_OFF + ((size_t)lb_a*16 + (fg ^ sw))*16);
                    float4 v = *(const float4*)(smem + XS_OFF + ((size_t)lb_a*16 + ((fg+1) ^ sw))*16);
                    half8 a = (half8){(f16)u.x,(f16)u.y,(f16)u.z,(f16)u.w,
                                      (f16)v.x,(f16)v.y,(f16)v.z,(f16)v.w};
                    acc[0][m] = MFMA16(a, wrx[0], acc[0][m]);
                    acc[1][m] = MFMA16(a, wrx[1], acc[1][m]);
                }
                #pragma unroll
                for (int k = 0; k < 4; ++k) {
                    const int kc = kq*16 + k*4 + quad;
                    half8 a = frag_pk(smem + H1W_OFF + WB(kc>>1, lb_a, (kc&1)*3));
                    acc[0][m] = MFMA16(a, wrh[0][k], acc[0][m]);
                    acc[1][m] = MFMA16(a, wrh[1][k], acc[1][m]);
                }
            }
            #pragma unroll
            for (int gi = 0; gi < 2; ++gi) {
                const int g = gp*2 + gi;
                #pragma unroll
                for (int m = 0; m < 2; ++m)
                    #pragma unroll
                    for (int r = 0; r < 4; ++r)
                        RED[kq*2048 + g*512 + (m*16 + quad*4 + r)*16 + col] = acc[gi][m][r];
            }
            barrier_lds();
            {   // 4-way kq sum + pointwise -> HB
                float gt[4];
                #pragma unroll
                for (int g = 0; g < 4; ++g)
                    gt[g] = RED[       g*512 + tid] + RED[2048 + g*512 + tid]
                          + RED[4096 + g*512 + tid] + RED[6144 + g*512 + tid] + bsr[g];
                const float i_ = sigmoidf_(gt[0]);
                const float f_ = sigmoidf_(gt[1]);
                const float g_ = tanhf_(gt[2]);
                const float o_ = sigmoidf_(gt[3]);
                const float cn = f_ * CC[tid] + i_ * g_;
                CC[tid] = cn;
                ((f16*)(smem + HB_OFF))[tid] = (f16)(o_ * tanhf_(cn));
            }
            barrier_lds();
            // publish h1[t]: system copy always (L2 consumes); ring copy if coherent
            if (tid < 192) {
                u64 wv = (u64)hb[pc0] | ((u64)hb[pc0+1] << 16)
                       | ((pj < 2) ? ((u64)hb[pc0+2] << 32) : 0)
                       | ((u64)(u32)(t + 1) << 48);
                astore8w(h1w + (size_t)((t & 7)*2 + bhalf)*NWORD + jt*192 + tid, wv);
                if (coh) astore8a(rbuf + (size_t)(t & 7)*NWORD + jt*192 + tid, wv);
            }
            const bool needA2 = (tid == 0) && (t + 1 < T_) && (t + 1 >= SLOTS);
            u32 fA2 = needA2 ? flag_peek(a2 + (t + 1 - SLOTS)) : 32u;
            if (t + 1 < T_) {
                *(float4*)(smem + XS_OFF + tid*16) = xreg;
                stage_poll_r(smem, H1W_OFF, rbuf + (size_t)(t & 7)*NWORD,
                             h1w + (size_t)((t & 7)*2 + bhalf)*NWORD,
                             (u32)(t + 1), tid, soff, coh, esc);
            }
            if (needA2 && fA2 < 32u) wait_ge(a2 + (t + 1 - SLOTS), 32u);
            barrier_lds();
        }
    } else if (role < 128) {
        // ================= layer 2 =================
        const int v = role - 64;
        const int bhalf = v >> 5, jt = v & 31;
        u64* rbuf = hring + (size_t)(2 + bhalf) * RSLOT;   // ring 2/3
        int* esc  = (int*)(smem + XS_OFF);                 // L2 never uses XS
        if (tid == 0) *esc = 0;
        const int gp = w & 1, kq = w >> 1;
        half8 wrA[2][4], wrB[2][4];
        #pragma unroll
        for (int gi = 0; gi < 2; ++gi)
            #pragma unroll
            for (int k = 0; k < 4; ++k) {
                const int ktA = kq*4 + k;
                const int ktB = 16 + kq*4 + k;
                wrA[gi][k] = *(const half8*)(W2p + ((size_t)(((gp*2+gi)*32 + jt)*32 + ktA)*64 + lane)*8);
                wrB[gi][k] = *(const half8*)(W2p + ((size_t)(((gp*2+gi)*32 + jt)*32 + ktB)*64 + lane)*8);
            }
        float bsr[4];
        #pragma unroll
        for (int g = 0; g < 4; ++g) bsr[g] = bs2[g*512 + jt*16 + (tid & 15)];
        CC[tid] = 0.f;

        u32* a2 = arr2 + bhalf*1024;
        u32* aH = arrH + bhalf*1024;

        // prologue: h1[0] (system, tag 1) then h2[-1] (ring/system, slot 7 tag 0)
        __syncthreads();   // esc visible
        stage_poll(smem, H1W_OFF, h1w + (size_t)(0*2 + bhalf)*NWORD, 1u, tid, soff);
        stage_poll_r(smem, H2W_OFF, rbuf + (size_t)7*NWORD,
                     h2w + (size_t)(7*2 + bhalf)*NWORD, 0u, tid, soff, coh, esc);
        __syncthreads();

        for (int t2 = 0; t2 < T_; ++t2) {
            floatx4 acc[2][2] = {{{0.f,0.f,0.f,0.f},{0.f,0.f,0.f,0.f}},
                                 {{0.f,0.f,0.f,0.f},{0.f,0.f,0.f,0.f}}};
            #pragma unroll
            for (int m = 0; m < 2; ++m) {   // pass A (h1[t2])
                const int lb_a = m*16 + col;
                #pragma unroll
                for (int k = 0; k < 4; ++k) {
                    const int kc = kq*16 + k*4 + quad;
                    half8 a = frag_pk(smem + H1W_OFF + WB(kc>>1, lb_a, (kc&1)*3));
                    acc[0][m] = MFMA16(a, wrA[0][k], acc[0][m]);
                    acc[1][m] = MFMA16(a, wrA[1][k], acc[1][m]);
                }
            }
            // EARLY ISSUE: h1[t2+1] system loads -> registers. With lgkm-only
            // barriers these ride across RED/pointwise/publish and are first
            // waited at the tail commit (~2us later) -- genuinely hidden now.
            u64 h1r[12];
            const u64* g1n = h1w + (size_t)(((t2+1) & 7)*2 + bhalf)*NWORD;
            if (t2 + 1 < T_) {
                #pragma unroll
                for (int i = 0; i < 12; ++i) h1r[i] = aload8w(g1n + i*512 + tid);
            }
            #pragma unroll
            for (int m = 0; m < 2; ++m) {   // pass B (h2[t2-1])
                const int lb_a = m*16 + col;
                #pragma unroll
                for (int k = 0; k < 4; ++k) {
                    const int kc = kq*16 + k*4 + quad;
                    half8 a = frag_pk(smem + H2W_OFF + WB(kc>>1, lb_a, (kc&1)*3));
                    acc[0][m] = MFMA16(a, wrB[0][k], acc[0][m]);
                    acc[1][m] = MFMA16(a, wrB[1][k], acc[1][m]);
                }
            }
            #pragma unroll
            for (int gi = 0; gi < 2; ++gi) {
                const int g = gp*2 + gi;
                #pragma unroll
                for (int m = 0; m < 2; ++m)
                    #pragma unroll
                    for (int r = 0; r < 4; ++r)
                        RED[kq*2048 + g*512 + (m*16 + quad*4 + r)*16 + col] = acc[gi][m][r];
            }
            barrier_lds();
            {   // 4-way kq sum + pointwise -> HB
                float gt[4];
                #pragma unroll
                for (int g = 0; g < 4; ++g)
                    gt[g] = RED[       g*512 + tid] + RED[2048 + g*512 + tid]
                          + RED[4096 + g*512 + tid] + RED[6144 + g*512 + tid] + bsr[g];
                const float i_ = sigmoidf_(gt[0]);
                const float f_ = sigmoidf_(gt[1]);
                const float g_ = tanhf_(gt[2]);
                const float o_ = sigmoidf_(gt[3]);
                const float cn = f_ * CC[tid] + i_ * g_;
                CC[tid] = cn;
                ((f16*)(smem + HB_OFF))[tid] = (f16)(o_ * tanhf_(cn));
            }
            barrier_lds();
            // publish h2[t2]: system copy always (head consumes); ring copy if coherent
            if (tid < 192) {
                u64 wv = (u64)hb[pc0] | ((u64)hb[pc0+1] << 16)
                       | ((pj < 2) ? ((u64)hb[pc0+2] << 32) : 0)
                       | ((u64)(u32)(t2 + 1) << 48);
                astore8w(h2w + (size_t)((t2 & 7)*2 + bhalf)*NWORD + jt*192 + tid, wv);
                if (coh) astore8a(rbuf + (size_t)(t2 & 7)*NWORD + jt*192 + tid, wv);
            }
            if (tid == 0) flag_add(a2 + t2);
            const bool needAH = (tid == 0) && (t2 + 1 < T_) && (t2 + 1 >= SLOTS);
            u32 fAH = needAH ? flag_peek(aH + (t2 + 1 - SLOTS)) : 1u;
            if (t2 + 1 < T_) {
                // commit h1[t2+1] (loads issued after pass A; waited HERE only)
                u32 pend = 0xFFFu;
                #pragma unroll
                for (int i = 0; i < 12; ++i) {
                    if ((u32)(h1r[i] >> 48) == (u32)(t2 + 2)) {
                        *(u64*)(smem + H1W_OFF + soff[i]) = h1r[i];
                        pend &= ~(1u << i);
                    }
                }
                while (pend) {   // rare (warm-up): straggler re-poll
                    u64 vv[12];
                    #pragma unroll
                    for (int i = 0; i < 12; ++i) vv[i] = aload8w(g1n + i*512 + tid);
                    #pragma unroll
                    for (int i = 0; i < 12; ++i) {
                        if ((pend & (1u << i)) && (u32)(vv[i] >> 48) == (u32)(t2 + 2)) {
                            *(u64*)(smem + H1W_OFF + soff[i]) = vv[i];
                            pend &= ~(1u << i);
                        }
                    }
                    if (pend) __builtin_amdgcn_s_sleep(1);
                }
                // live edge: h2[t2] ring poll
                stage_poll_r(smem, H2W_OFF, rbuf + (size_t)(t2 & 7)*NWORD,
                             h2w + (size_t)((t2 & 7)*2 + bhalf)*NWORD,
                             (u32)(t2 + 1), tid, soff, coh, esc);
            }
            if (needAH && fAH < 1u) wait_ge(aH + (t2 + 1 - SLOTS), 1u);
            barrier_lds();
        }
    } else {
        // ================= head =================
        const int bhalf = role - 128;
        const int nt = w & 3, kh = w >> 2;
        half8 wr[8];
        #pragma unroll
        for (int k = 0; k < 8; ++k) {
            const int kt = kh*8 + k;
            wr[k] = *(const half8*)(Wop + ((size_t)(nt*16 + kt)*64 + lane)*8);
        }
        const float boutr = bout[nt*16 + col];
        u32* aH = arrH + bhalf*1024;
        const int lb0 = col, lb1 = 16 + col;

        stage_poll(smem, H1W_OFF, h2w + (size_t)(0*2 + bhalf)*NWORD, 1u, tid, soff);
        __syncthreads();
        if (tid == 0) flag_add(aH + 0);

        for (int t3 = 0; t3 < T_; ++t3) {
            floatx4 acc0 = {0.f,0.f,0.f,0.f}, acc1 = {0.f,0.f,0.f,0.f};
            #pragma unroll
            for (int k = 0; k < 8; ++k) {
                const int kc = (kh*8 + k)*4 + quad;
                half8 a0  = frag_pk(smem + H1W_OFF + WB(kc>>1, lb0, (kc&1)*3));
                half8 a1v = frag_pk(smem + H1W_OFF + WB(kc>>1, lb1, (kc&1)*3));
                acc0 = MFMA16(a0,  wr[k], acc0);
                acc1 = MFMA16(a1v, wr[k], acc1);
            }
            if (kh == 1) {
                #pragma unroll
                for (int r = 0; r < 4; ++r) {
                    RED[(nt*2+0)*256 + (quad*4 + r)*16 + col] = acc0[r];
                    RED[(nt*2+1)*256 + (quad*4 + r)*16 + col] = acc1[r];
                }
            }
            __syncthreads();
            if (kh == 0) {
                #pragma unroll
                for (int r = 0; r < 4; ++r) {
                    const float v0 = acc0[r] + RED[(nt*2+0)*256 + (quad*4 + r)*16 + col] + boutr;
                    const float v1 = acc1[r] + RED[(nt*2+1)*256 + (quad*4 + r)*16 + col] + boutr;
                    const int b0 = bhalf*32 +  0 + quad*4 + r;
                    const int b1 = bhalf*32 + 16 + quad*4 + r;
                    y[((size_t)b0*T_ + t3)*OUT_ + nt*16 + col] = v0;
                    y[((size_t)b1*T_ + t3)*OUT_ + nt*16 + col] = v1;
                }
            }
            __syncthreads();
            if (t3 + 1 < T_) {
                stage_poll(smem, H1W_OFF, h2w + (size_t)(((t3+1) & 7)*2 + bhalf)*NWORD,
                           (u32)(t3 + 2), tid, soff);
                __syncthreads();
                if (tid == 0) flag_add(aH + (t3 + 1));
            }
        }
    }
}

// ---------------- launch ----------------
extern "C" void kernel_launch(void* const* d_in, const int* in_sizes, int n_in,
                              void* d_out, int out_size, void* d_ws, size_t ws_size,
                              hipStream_t stream) {
    const float* x    = (const float*)d_in[0];
    const float* Wih1 = (const float*)d_in[1];
    const float* Whh1 = (const float*)d_in[2];
    const float* bih1 = (const float*)d_in[3];
    const float* bhh1 = (const float*)d_in[4];
    const float* Wih2 = (const float*)d_in[5];
    const float* Whh2 = (const float*)d_in[6];
    const float* bih2 = (const float*)d_in[7];
    const float* bhh2 = (const float*)d_in[8];
    const float* Wout = (const float*)d_in[9];
    const float* bout = (const float*)d_in[10];
    float* y = (float*)d_out;

    char* ws = (char*)d_ws;
    f16*   W1p   = (f16*)(ws + 0);           // 2,359,296 B
    f16*   W2p   = (f16*)(ws + 2359296);     // 4,194,304 B
    f16*   Wop   = (f16*)(ws + 6553600);     //    65,536 B
    float* bs1   = (float*)(ws + 6619136);   //     8,192 B
    float* bs2   = (float*)(ws + 6627328);   //     8,192 B
    u64*   h1w   = (u64*)(ws + 6635520);     //   786,432 B
    u64*   h2w   = (u64*)(ws + 7421952);     //   786,432 B
    u32*   arr2  = (u32*)(ws + 8208384);     //     8,192 B
    u32*   arrH  = (u32*)(ws + 8216576);     //     8,192 B
    u64*   hring = (u64*)(ws + 8224768);     // 1,572,864 B (4 rings x 8 slots)
    u32*   ctrl  = (u32*)(ws + 9797632);     //     1,168 B

    // zero tagged buffers (tag 0 = step -1 state), counters, rings, ctrl
    hipMemsetAsync(ws + 6635520, 0, 3163280, stream);

    pack_w1<<<4608, 256, 0, stream>>>(Wih1, Whh1, W1p);
    pack_w2<<<8192, 256, 0, stream>>>(Wih2, Whh2, W2p);
    pack_wo<<<128, 256, 0, stream>>>(Wout, Wop);
    bias_sum<<<8, 256, 0, stream>>>(bih1, bhh1, bih2, bhh2, bs1, bs2);

    lstm_persist<<<NWG, 512, 0, stream>>>(x, W1p, W2p, Wop, bs1, bs2, bout,
                                          h1w, h2w, hring, y, arr2, arrH, ctrl);
}